// Round 2
// baseline (1402.011 us; speedup 1.0000x reference)
//
#include <hip/hip_runtime.h>
#include <cstdint>
#include <cstddef>

typedef unsigned short u16;
typedef short bf16x8 __attribute__((ext_vector_type(8)));
typedef float f32x4 __attribute__((ext_vector_type(4)));

__device__ __forceinline__ float bf2f(u16 v) {
  union { unsigned int u; float f; } x; x.u = ((unsigned int)v) << 16; return x.f;
}
__device__ __forceinline__ u16 f2bf(float f) {
  union { float f; unsigned int u; } x; x.f = f;
  unsigned int r = (x.u + 0x7fffu + ((x.u >> 16) & 1u)) >> 16;
  return (u16)r;
}

__device__ __forceinline__ void async16(const u16* g, u16* lds) {
  __builtin_amdgcn_global_load_lds(
      (const __attribute__((address_space(1))) void*)g,
      (__attribute__((address_space(3))) void*)lds, 16, 0, 0);
}

// ---------------------------------------------------------------------------
// GEMM: C[M][N] = A[M][K] @ Bt[N][K]^T + bias[N]   (bf16 in, f32 acc, bf16 out)
// 128x128 block tile, BK=64, 4 waves each 64x64 (4x4 of 16x16x32 MFMA).
// M, N, K multiples of 128 (all shapes here are).
// ---------------------------------------------------------------------------
#define BM 128
#define BN 128
#define BK 64

__global__ __launch_bounds__(256) void gemm_bt(
    const u16* __restrict__ A, const u16* __restrict__ Bt,
    const float* __restrict__ bias, u16* __restrict__ C,
    int M, int N, int K)
{
  __shared__ __align__(16) u16 As[BM * BK];
  __shared__ __align__(16) u16 Bs[BN * BK];
  const int tid = threadIdx.x;
  const int w   = tid >> 6;
  const int l   = tid & 63;
  const int bm  = blockIdx.x;
  const int bn  = blockIdx.y;
  const int wm  = w >> 1;
  const int wn  = w & 1;
  const int tRow = l & 15;
  const int quad = l >> 4;

  // staging: 16 segments of 8 rows; segment s = i*4 + w; lane covers
  // row s*8 + (l>>3), 16B at col (l&7)*8.  LDS dst = wave-uniform base + lane*16.
  const u16* ag[4]; const u16* bg[4];
  u16* al[4]; u16* bl[4];
  #pragma unroll
  for (int i = 0; i < 4; ++i) {
    int s = i * 4 + w;
    int row = s * 8 + (l >> 3);
    ag[i] = A  + (size_t)(bm * BM + row) * K + (l & 7) * 8;
    bg[i] = Bt + (size_t)(bn * BN + row) * K + (l & 7) * 8;
    al[i] = &As[s * 512];
    bl[i] = &Bs[s * 512];
  }

  f32x4 acc[4][4] = {};

  for (int k0 = 0; k0 < K; k0 += BK) {
    __syncthreads();
    #pragma unroll
    for (int i = 0; i < 4; ++i) {
      async16(ag[i], al[i]);
      async16(bg[i], bl[i]);
      ag[i] += BK; bg[i] += BK;
    }
    __syncthreads();   // barrier drains vmcnt(0) -> LDS tiles ready
    #pragma unroll
    for (int ks = 0; ks < BK; ks += 32) {
      bf16x8 af[4], bfr[4];
      #pragma unroll
      for (int mt = 0; mt < 4; ++mt)
        af[mt] = *(const bf16x8*)&As[(wm * 64 + mt * 16 + tRow) * BK + ks + quad * 8];
      #pragma unroll
      for (int nt = 0; nt < 4; ++nt)
        bfr[nt] = *(const bf16x8*)&Bs[(wn * 64 + nt * 16 + tRow) * BK + ks + quad * 8];
      #pragma unroll
      for (int mt = 0; mt < 4; ++mt)
        #pragma unroll
        for (int nt = 0; nt < 4; ++nt)
          acc[mt][nt] = __builtin_amdgcn_mfma_f32_16x16x32_bf16(af[mt], bfr[nt], acc[mt][nt], 0, 0, 0);
    }
  }

  // epilogue: C/D layout col = lane&15, row = quad*4 + reg  (m89/m91 verified)
  const int crow0 = bm * BM + wm * 64;
  const int ccol0 = bn * BN + wn * 64;
  #pragma unroll
  for (int nt = 0; nt < 4; ++nt) {
    int col = ccol0 + nt * 16 + tRow;
    float bv = bias[col];
    #pragma unroll
    for (int mt = 0; mt < 4; ++mt) {
      int r0 = crow0 + mt * 16 + quad * 4;
      #pragma unroll
      for (int r = 0; r < 4; ++r)
        C[(size_t)(r0 + r) * N + col] = f2bf(acc[mt][nt][r] + bv);
    }
  }
}

// ---------------------------------------------------------------------------
// Fused convert+transpose: src f32 [R][C] -> dst bf16 [C][R]. R,C mult of 64.
// ---------------------------------------------------------------------------
__global__ __launch_bounds__(256) void transpose_f2bf(
    const float* __restrict__ src, u16* __restrict__ dst, int R, int C)
{
  __shared__ __align__(16) u16 tile[64][72];
  const int bx = blockIdx.x;  // over C/64
  const int by = blockIdx.y;  // over R/64
  const int t = threadIdx.x;
  const int r  = t >> 4;          // 0..15
  const int c4 = (t & 15) * 4;
  #pragma unroll
  for (int i = 0; i < 4; ++i) {
    int row = r + i * 16;
    f32x4 v = *(const f32x4*)&src[(size_t)(by * 64 + row) * C + bx * 64 + c4];
    #pragma unroll
    for (int j = 0; j < 4; ++j) tile[row][c4 + j] = f2bf(v[j]);
  }
  __syncthreads();
  const int orow0 = t >> 3;       // 0..31
  const int oc8   = (t & 7) * 8;
  #pragma unroll
  for (int i = 0; i < 2; ++i) {
    int orow = orow0 + i * 32;    // source column
    u16 tmp[8];
    #pragma unroll
    for (int j = 0; j < 8; ++j) tmp[j] = tile[oc8 + j][orow];
    *(uint4*)&dst[(size_t)(bx * 64 + orow) * R + by * 64 + oc8] = *(uint4*)tmp;
  }
}

// ---------------------------------------------------------------------------
// Small helpers (all f32 inputs)
// ---------------------------------------------------------------------------
__global__ void cvt_f2bf(const float* __restrict__ s, u16* __restrict__ d) {
  size_t i = ((size_t)blockIdx.x * 256 + threadIdx.x) * 8;
  f32x4 a = *(const f32x4*)&s[i];
  f32x4 b = *(const f32x4*)&s[i + 4];
  u16 o[8];
  #pragma unroll
  for (int j = 0; j < 4; ++j) { o[j] = f2bf(a[j]); o[j + 4] = f2bf(b[j]); }
  *(uint4*)&d[i] = *(uint4*)o;
}

__global__ void mod_k(const float* __restrict__ ph, float* __restrict__ m, int n) {
  int i = blockIdx.x * 256 + threadIdx.x;
  if (i < n) { float p = ph[i]; m[i] = cosf(p) + sinf(p); }
}

// WcT[f][d] = sum_p pw[p][d][f] * mod[p][f]  (combined interference weight, bf16, transposed)
__global__ __launch_bounds__(256) void combine_path_k(
    const float* __restrict__ pw, const float* __restrict__ mod,
    u16* __restrict__ WcT, int D)
{
  __shared__ float tile[64][65];   // [d_local][f_local]
  const int bx = blockIdx.x;  // f tile
  const int by = blockIdx.y;  // d tile
  const int t = threadIdx.x;
  const int r  = t >> 4;          // 0..15
  const int c4 = (t & 15) * 4;
  float acc[4][4];
  #pragma unroll
  for (int i = 0; i < 4; ++i)
    #pragma unroll
    for (int j = 0; j < 4; ++j) acc[i][j] = 0.f;
  for (int p = 0; p < 2; ++p) {
    float m[4];
    #pragma unroll
    for (int j = 0; j < 4; ++j) m[j] = mod[p * D + bx * 64 + c4 + j];
    #pragma unroll
    for (int i = 0; i < 4; ++i) {
      int d = by * 64 + r + i * 16;
      f32x4 v = *(const f32x4*)&pw[((size_t)p * D + d) * D + bx * 64 + c4];
      #pragma unroll
      for (int j = 0; j < 4; ++j) acc[i][j] += v[j] * m[j];
    }
  }
  #pragma unroll
  for (int i = 0; i < 4; ++i)
    #pragma unroll
    for (int j = 0; j < 4; ++j) tile[r + i * 16][c4 + j] = acc[i][j];
  __syncthreads();
  const int fo0 = t >> 3;         // 0..31
  const int oc8 = (t & 7) * 8;
  #pragma unroll
  for (int i = 0; i < 2; ++i) {
    int fo = fo0 + i * 32;
    u16 tmp[8];
    #pragma unroll
    for (int j = 0; j < 8; ++j) tmp[j] = f2bf(tile[oc8 + j][fo]);
    *(uint4*)&WcT[(size_t)(bx * 64 + fo) * D + by * 64 + oc8] = *(uint4*)tmp;
  }
}

__global__ void combine_bias_k(const float* __restrict__ pb, const float* __restrict__ mod,
                               float* __restrict__ bc, int D) {
  int f = blockIdx.x * 256 + threadIdx.x;
  if (f < D) bc[f] = pb[f] * mod[f] + pb[D + f] * mod[D + f];
}

// h = (cos(pi*tanh(z2)) + sin(pi*tanh(z2))) * sigmoid(z1)   (bf16 in/out)
__global__ __launch_bounds__(256) void superpose_k(
    const u16* __restrict__ z1, const u16* __restrict__ z2, u16* __restrict__ h)
{
  size_t i = ((size_t)blockIdx.x * 256 + threadIdx.x) * 8;
  uint4 v1 = *(const uint4*)&z1[i];
  uint4 v2 = *(const uint4*)&z2[i];
  const u16* p1 = (const u16*)&v1;
  const u16* p2 = (const u16*)&v2;
  u16 o[8];
  #pragma unroll
  for (int j = 0; j < 8; ++j) {
    float a = bf2f(p1[j]);
    float p = bf2f(p2[j]);
    float amp = 1.f / (1.f + __expf(-a));
    float ph = 3.14159265358979323f * tanhf(p);
    float s, c;
    __sincosf(ph, &s, &c);
    o[j] = f2bf((c + s) * amp);
  }
  *(uint4*)&h[i] = *(uint4*)o;
}

// out = LayerNorm(hin + delta) * g + b   (one block per row, D=2048; g,b f32)
template <bool F32OUT>
__global__ __launch_bounds__(256) void add_ln_k(
    const u16* __restrict__ hin, const u16* __restrict__ delta,
    const float* __restrict__ g, const float* __restrict__ b,
    void* __restrict__ outp, int D)
{
  const int row = blockIdx.x;
  const int t = threadIdx.x;
  const size_t base = (size_t)row * D;
  uint4 hv = *(const uint4*)&hin[base + t * 8];
  uint4 dv = *(const uint4*)&delta[base + t * 8];
  const u16* hp = (const u16*)&hv;
  const u16* dp = (const u16*)&dv;
  float x[8];
  float s = 0.f, s2 = 0.f;
  #pragma unroll
  for (int j = 0; j < 8; ++j) {
    x[j] = bf2f(hp[j]) + bf2f(dp[j]);
    s += x[j]; s2 += x[j] * x[j];
  }
  #pragma unroll
  for (int o = 32; o > 0; o >>= 1) {
    s  += __shfl_down(s, o, 64);
    s2 += __shfl_down(s2, o, 64);
  }
  __shared__ float ss[4], ss2[4];
  if ((t & 63) == 0) { ss[t >> 6] = s; ss2[t >> 6] = s2; }
  __syncthreads();
  float S  = ss[0] + ss[1] + ss[2] + ss[3];
  float S2 = ss2[0] + ss2[1] + ss2[2] + ss2[3];
  float mean = S / D;
  float var = S2 / D - mean * mean;
  float rstd = rsqrtf(var + 1e-5f);
  float y[8];
  #pragma unroll
  for (int j = 0; j < 8; ++j)
    y[j] = (x[j] - mean) * rstd * g[t * 8 + j] + b[t * 8 + j];
  if constexpr (F32OUT) {
    float* out = (float*)outp;
    f32x4 lo = {y[0], y[1], y[2], y[3]};
    f32x4 hi = {y[4], y[5], y[6], y[7]};
    *(f32x4*)&out[base + t * 8]     = lo;
    *(f32x4*)&out[base + t * 8 + 4] = hi;
  } else {
    u16* out = (u16*)outp;
    u16 o8[8];
    #pragma unroll
    for (int j = 0; j < 8; ++j) o8[j] = f2bf(y[j]);
    *(uint4*)&out[base + t * 8] = *(uint4*)o8;
  }
}

// ---------------------------------------------------------------------------
extern "C" void kernel_launch(void* const* d_in, const int* in_sizes, int n_in,
                              void* d_out, int out_size, void* d_ws, size_t ws_size,
                              hipStream_t stream) {
  // All reference dtypes are float32.
  const float* x      = (const float*)d_in[0];
  const float* amp_w  = (const float*)d_in[1];
  const float* amp_b  = (const float*)d_in[2];
  const float* ph_w   = (const float*)d_in[3];
  const float* ph_b   = (const float*)d_in[4];
  const float* ent_w  = (const float*)d_in[5];
  const float* ent_b  = (const float*)d_in[6];
  const float* ent_pw = (const float*)d_in[7];
  const float* ent_pb = (const float*)d_in[8];
  const float* path_w = (const float*)d_in[9];
  const float* path_b = (const float*)d_in[10];
  const float* phase  = (const float*)d_in[11];
  const float* ln3_g  = (const float*)d_in[12];
  const float* ln3_b  = (const float*)d_in[13];
  const float* ln4_g  = (const float*)d_in[14];
  const float* ln4_b  = (const float*)d_in[15];

  constexpr int D = 2048, PD = 8192, M = 4096, L = 2, PW = 2;

  // Workspace arena (~134.3 MB):
  char* p = (char*)d_ws;
  u16* wT = (u16*)p; p += (size_t)PD * D * sizeof(u16);   // 33.5 MB transposed bf16 weight (reused)
  u16* h  = (u16*)p; p += (size_t)M * D * sizeof(u16);    // 16.8 MB
  u16* t1 = (u16*)p; p += (size_t)M * D * sizeof(u16);    // 16.8 MB
  u16* e  = (u16*)p; p += (size_t)M * PD * sizeof(u16);   // 67 MB; pre-loop hosts xb/z1/z2
  float* modf = (float*)p; p += (size_t)L * PW * D * sizeof(float);
  float* bcf  = (float*)p; p += (size_t)D * sizeof(float);

  u16* xb = e;                      // bf16 copy of x  (dead once z1/z2 computed)
  u16* z1 = e + (size_t)M * D;      // sigmoid pre-act
  u16* z2 = e + (size_t)2 * M * D;  // phase pre-act

  dim3 b256(256);

  mod_k<<<(L * PW * D) / 256, b256, 0, stream>>>(phase, modf, L * PW * D);
  cvt_f2bf<<<(M * D) / (256 * 8), b256, 0, stream>>>(x, xb);

  // superposition: z1 = x@amp_w+amp_b ; z2 = x@ph_w+ph_b ; h = f(z1,z2)
  transpose_f2bf<<<dim3(D / 64, D / 64), b256, 0, stream>>>(amp_w, wT, D, D);
  gemm_bt<<<dim3(M / BM, D / BN), b256, 0, stream>>>(xb, wT, amp_b, z1, M, D, D);
  transpose_f2bf<<<dim3(D / 64, D / 64), b256, 0, stream>>>(ph_w, wT, D, D);
  gemm_bt<<<dim3(M / BM, D / BN), b256, 0, stream>>>(xb, wT, ph_b, z2, M, D, D);
  superpose_k<<<(M * D) / (256 * 8), b256, 0, stream>>>(z1, z2, h);

  for (int l = 0; l < L; ++l) {
    // e = h @ ent_w[l] + ent_b[l]                      [M, PD]
    transpose_f2bf<<<dim3(PD / 64, D / 64), b256, 0, stream>>>(ent_w + (size_t)l * D * PD, wT, D, PD);
    gemm_bt<<<dim3(M / BM, PD / BN), b256, 0, stream>>>(h, wT, ent_b + (size_t)l * PD, e, M, PD, D);
    // ent = e @ ent_pw[l] + ent_pb[l]                  [M, D]
    transpose_f2bf<<<dim3(D / 64, PD / 64), b256, 0, stream>>>(ent_pw + (size_t)l * PD * D, wT, PD, D);
    gemm_bt<<<dim3(M / BM, D / BN), b256, 0, stream>>>(e, wT, ent_pb + (size_t)l * D, t1, M, D, PD);
    // h = LN(h + ent)
    add_ln_k<false><<<M, b256, 0, stream>>>(h, t1, ln3_g + (size_t)l * D, ln3_b + (size_t)l * D, h, D);
    // interf = h @ Wc + bc   (PW=2 pathways folded into one matrix)
    combine_path_k<<<dim3(D / 64, D / 64), b256, 0, stream>>>(
        path_w + (size_t)l * PW * D * D, modf + (size_t)l * PW * D, wT, D);
    combine_bias_k<<<D / 256, b256, 0, stream>>>(path_b + (size_t)l * PW * D, modf + (size_t)l * PW * D, bcf, D);
    gemm_bt<<<dim3(M / BM, D / BN), b256, 0, stream>>>(h, wT, bcf, t1, M, D, D);
    // h = LN(h + interf); final layer writes f32 d_out
    if (l == L - 1)
      add_ln_k<true><<<M, b256, 0, stream>>>(h, t1, ln4_g + (size_t)l * D, ln4_b + (size_t)l * D, d_out, D);
    else
      add_ln_k<false><<<M, b256, 0, stream>>>(h, t1, ln4_g + (size_t)l * D, ln4_b + (size_t)l * D, h, D);
  }
}

// Round 4
// 1293.424 us; speedup vs baseline: 1.0840x; 1.0840x over previous
//
#include <hip/hip_runtime.h>
#include <cstdint>
#include <cstddef>

typedef unsigned short u16;
typedef short bf16x8 __attribute__((ext_vector_type(8)));
typedef float f32x4 __attribute__((ext_vector_type(4)));

__device__ __forceinline__ float bf2f(u16 v) {
  union { unsigned int u; float f; } x; x.u = ((unsigned int)v) << 16; return x.f;
}
__device__ __forceinline__ u16 f2bf(float f) {
  union { float f; unsigned int u; } x; x.f = f;
  unsigned int r = (x.u + 0x7fffu + ((x.u >> 16) & 1u)) >> 16;
  return (u16)r;
}

__device__ __forceinline__ void async16(const u16* g, u16* lds) {
  __builtin_amdgcn_global_load_lds(
      (const __attribute__((address_space(1))) void*)g,
      (__attribute__((address_space(3))) void*)lds, 16, 0, 0);
}

// ---------------------------------------------------------------------------
// GEMM: C[M][N](stride ldc) = A[M][K](stride lda) @ Bt[N][K]^T (+ bias | + C)
// bf16 in, f32 acc, bf16 out. 128x128 tile, BK=64, 4 waves of 64x64.
// ACC=false: C = A@Bt^T + bias ;  ACC=true: C += A@Bt^T  (bias ignored).
// XOR bank swizzle: logical 16B chunk c of tile row r stored at physical
// chunk c^(r&7); staging permutes which global chunk each lane fetches
// (wave-uniform LDS base + lane*16 preserved).
// ---------------------------------------------------------------------------
#define BM 128
#define BN 128
#define BK 64

template <bool ACC>
__global__ __launch_bounds__(256) void gemm_bt(
    const u16* __restrict__ A, int lda,
    const u16* __restrict__ Bt,
    const float* __restrict__ bias,
    u16* __restrict__ C, int ldc,
    int M, int N, int K)
{
  __shared__ __align__(16) u16 As[BM * BK];
  __shared__ __align__(16) u16 Bs[BN * BK];
  const int tid = threadIdx.x;
  const int w   = tid >> 6;
  const int l   = tid & 63;
  const int bm  = blockIdx.x;
  const int bn  = blockIdx.y;
  const int wm  = w >> 1;
  const int wn  = w & 1;
  const int tRow = l & 15;
  const int quad = l >> 4;

  const u16* ag[4]; const u16* bg[4];
  u16* al[4]; u16* bl[4];
  #pragma unroll
  for (int i = 0; i < 4; ++i) {
    int s = i * 4 + w;
    int row = s * 8 + (l >> 3);
    int c   = (l & 7) ^ ((l >> 3) & 7);      // logical chunk this lane fetches
    ag[i] = A  + (size_t)(bm * BM + row) * lda + c * 8;
    bg[i] = Bt + (size_t)(bn * BN + row) * K   + c * 8;
    al[i] = &As[s * 512];
    bl[i] = &Bs[s * 512];
  }

  f32x4 acc[4][4] = {};

  for (int k0 = 0; k0 < K; k0 += BK) {
    __syncthreads();
    #pragma unroll
    for (int i = 0; i < 4; ++i) {
      async16(ag[i], al[i]);
      async16(bg[i], bl[i]);
      ag[i] += BK; bg[i] += BK;
    }
    __syncthreads();   // barrier drains vmcnt(0) -> LDS tiles ready
    #pragma unroll
    for (int ks = 0; ks < BK; ks += 32) {
      const int lc = (ks >> 3) + quad;       // logical chunk for this frag
      bf16x8 af[4], bfr[4];
      #pragma unroll
      for (int mt = 0; mt < 4; ++mt) {
        int r = wm * 64 + mt * 16 + tRow;
        int p = lc ^ (tRow & 7);             // r&7 == tRow&7
        af[mt] = *(const bf16x8*)&As[r * BK + p * 8];
      }
      #pragma unroll
      for (int nt = 0; nt < 4; ++nt) {
        int r = wn * 64 + nt * 16 + tRow;
        int p = lc ^ (tRow & 7);
        bfr[nt] = *(const bf16x8*)&Bs[r * BK + p * 8];
      }
      #pragma unroll
      for (int mt = 0; mt < 4; ++mt)
        #pragma unroll
        for (int nt = 0; nt < 4; ++nt)
          acc[mt][nt] = __builtin_amdgcn_mfma_f32_16x16x32_bf16(af[mt], bfr[nt], acc[mt][nt], 0, 0, 0);
    }
  }

  // epilogue: C/D layout col = lane&15, row = quad*4 + reg (m89/m91 verified)
  const int crow0 = bm * BM + wm * 64;
  const int ccol0 = bn * BN + wn * 64;
  #pragma unroll
  for (int nt = 0; nt < 4; ++nt) {
    int col = ccol0 + nt * 16 + tRow;
    float bv = ACC ? 0.f : bias[col];
    #pragma unroll
    for (int mt = 0; mt < 4; ++mt) {
      int r0 = crow0 + mt * 16 + quad * 4;
      #pragma unroll
      for (int r = 0; r < 4; ++r) {
        size_t idx = (size_t)(r0 + r) * ldc + col;
        float v = acc[mt][nt][r] + bv;
        if (ACC) v += bf2f(C[idx]);
        C[idx] = f2bf(v);
      }
    }
  }
}

// ---------------------------------------------------------------------------
// Convert+transpose: dst[n][k] = f2bf(src[k*srcStride + col0 + n]),
// n in [0,C), k in [0,R). dst stride = R. grid (C/64, R/64), 256 thr.
// ---------------------------------------------------------------------------
__global__ __launch_bounds__(256) void transpose_f2bf(
    const float* __restrict__ src, u16* __restrict__ dst,
    int R, int C, int srcStride, int col0)
{
  __shared__ __align__(16) u16 tile[64][72];
  const int bx = blockIdx.x;  // over C/64 (dst rows)
  const int by = blockIdx.y;  // over R/64 (dst cols)
  const int t = threadIdx.x;
  const int r  = t >> 4;          // 0..15
  const int c4 = (t & 15) * 4;
  #pragma unroll
  for (int i = 0; i < 4; ++i) {
    int row = r + i * 16;
    f32x4 v = *(const f32x4*)&src[(size_t)(by * 64 + row) * srcStride + col0 + bx * 64 + c4];
    #pragma unroll
    for (int j = 0; j < 4; ++j) tile[row][c4 + j] = f2bf(v[j]);
  }
  __syncthreads();
  const int orow0 = t >> 3;       // 0..31
  const int oc8   = (t & 7) * 8;
  #pragma unroll
  for (int i = 0; i < 2; ++i) {
    int orow = orow0 + i * 32;    // source column
    u16 tmp[8];
    #pragma unroll
    for (int j = 0; j < 8; ++j) tmp[j] = tile[oc8 + j][orow];
    *(uint4*)&dst[(size_t)(bx * 64 + orow) * R + by * 64 + oc8] = *(uint4*)tmp;
  }
}

// ---------------------------------------------------------------------------
// Small helpers (all f32 inputs)
// ---------------------------------------------------------------------------
__global__ void cvt_f2bf(const float* __restrict__ s, u16* __restrict__ d) {
  size_t i = ((size_t)blockIdx.x * 256 + threadIdx.x) * 8;
  f32x4 a = *(const f32x4*)&s[i];
  f32x4 b = *(const f32x4*)&s[i + 4];
  u16 o[8];
  #pragma unroll
  for (int j = 0; j < 4; ++j) { o[j] = f2bf(a[j]); o[j + 4] = f2bf(b[j]); }
  *(uint4*)&d[i] = *(uint4*)o;
}

__global__ void mod_k(const float* __restrict__ ph, float* __restrict__ m, int n) {
  int i = blockIdx.x * 256 + threadIdx.x;
  if (i < n) { float p = ph[i]; m[i] = cosf(p) + sinf(p); }
}

__global__ void concat2_k(const float* __restrict__ a, const float* __restrict__ b,
                          float* __restrict__ d, int n) {
  int i = blockIdx.x * 256 + threadIdx.x;
  if (i < n) { d[i] = a[i]; d[n + i] = b[i]; }
}

// WcT[f][d] = sum_p pw[p][d][f] * mod[p][f]  (combined interference weight, bf16, transposed)
__global__ __launch_bounds__(256) void combine_path_k(
    const float* __restrict__ pw, const float* __restrict__ mod,
    u16* __restrict__ WcT, int D)
{
  __shared__ float tile[64][65];   // [d_local][f_local]
  const int bx = blockIdx.x;  // f tile
  const int by = blockIdx.y;  // d tile
  const int t = threadIdx.x;
  const int r  = t >> 4;          // 0..15
  const int c4 = (t & 15) * 4;
  float acc[4][4];
  #pragma unroll
  for (int i = 0; i < 4; ++i)
    #pragma unroll
    for (int j = 0; j < 4; ++j) acc[i][j] = 0.f;
  for (int p = 0; p < 2; ++p) {
    float m[4];
    #pragma unroll
    for (int j = 0; j < 4; ++j) m[j] = mod[p * D + bx * 64 + c4 + j];
    #pragma unroll
    for (int i = 0; i < 4; ++i) {
      int d = by * 64 + r + i * 16;
      f32x4 v = *(const f32x4*)&pw[((size_t)p * D + d) * D + bx * 64 + c4];
      #pragma unroll
      for (int j = 0; j < 4; ++j) acc[i][j] += v[j] * m[j];
    }
  }
  #pragma unroll
  for (int i = 0; i < 4; ++i)
    #pragma unroll
    for (int j = 0; j < 4; ++j) tile[r + i * 16][c4 + j] = acc[i][j];
  __syncthreads();
  const int fo0 = t >> 3;         // 0..31
  const int oc8 = (t & 7) * 8;
  #pragma unroll
  for (int i = 0; i < 2; ++i) {
    int fo = fo0 + i * 32;
    u16 tmp[8];
    #pragma unroll
    for (int j = 0; j < 8; ++j) tmp[j] = f2bf(tile[oc8 + j][fo]);
    *(uint4*)&WcT[(size_t)(bx * 64 + fo) * D + by * 64 + oc8] = *(uint4*)tmp;
  }
}

__global__ void combine_bias_k(const float* __restrict__ pb, const float* __restrict__ mod,
                               float* __restrict__ bc, int D) {
  int f = blockIdx.x * 256 + threadIdx.x;
  if (f < D) bc[f] = pb[f] * mod[f] + pb[D + f] * mod[D + f];
}

// h = (cos(pi*tanh(z2)) + sin(pi*tanh(z2))) * sigmoid(z1)
// zc is [M][2D]: z1 = cols [0,D), z2 = cols [D,2D).
__global__ __launch_bounds__(256) void superpose_k(
    const u16* __restrict__ zc, u16* __restrict__ h, int D)
{
  size_t idx = (size_t)blockIdx.x * 256 + threadIdx.x;   // over M*D/8 groups
  int grpPerRow = D / 8;
  size_t row = idx / grpPerRow;
  int cg = (int)(idx % grpPerRow);
  size_t zbase = row * (size_t)(2 * D) + cg * 8;
  uint4 v1 = *(const uint4*)&zc[zbase];
  uint4 v2 = *(const uint4*)&zc[zbase + D];
  const u16* p1 = (const u16*)&v1;
  const u16* p2 = (const u16*)&v2;
  u16 o[8];
  #pragma unroll
  for (int j = 0; j < 8; ++j) {
    float a = bf2f(p1[j]);
    float p = bf2f(p2[j]);
    float amp = 1.f / (1.f + __expf(-a));
    float ph = 3.14159265358979323f * tanhf(p);
    float s, c;
    __sincosf(ph, &s, &c);
    o[j] = f2bf((c + s) * amp);
  }
  *(uint4*)&h[row * D + cg * 8] = *(uint4*)o;
}

// out = LayerNorm(hin + delta) * g + b   (one block per row, D=2048; g,b f32)
template <bool F32OUT>
__global__ __launch_bounds__(256) void add_ln_k(
    const u16* __restrict__ hin, const u16* __restrict__ delta,
    const float* __restrict__ g, const float* __restrict__ b,
    void* __restrict__ outp, int D)
{
  const int row = blockIdx.x;
  const int t = threadIdx.x;
  const size_t base = (size_t)row * D;
  uint4 hv = *(const uint4*)&hin[base + t * 8];
  uint4 dv = *(const uint4*)&delta[base + t * 8];
  const u16* hp = (const u16*)&hv;
  const u16* dp = (const u16*)&dv;
  float x[8];
  float s = 0.f, s2 = 0.f;
  #pragma unroll
  for (int j = 0; j < 8; ++j) {
    x[j] = bf2f(hp[j]) + bf2f(dp[j]);
    s += x[j]; s2 += x[j] * x[j];
  }
  #pragma unroll
  for (int o = 32; o > 0; o >>= 1) {
    s  += __shfl_down(s, o, 64);
    s2 += __shfl_down(s2, o, 64);
  }
  __shared__ float ss[4], ss2[4];
  if ((t & 63) == 0) { ss[t >> 6] = s; ss2[t >> 6] = s2; }
  __syncthreads();
  float S  = ss[0] + ss[1] + ss[2] + ss[3];
  float S2 = ss2[0] + ss2[1] + ss2[2] + ss2[3];
  float mean = S / D;
  float var = S2 / D - mean * mean;
  float rstd = rsqrtf(var + 1e-5f);
  float y[8];
  #pragma unroll
  for (int j = 0; j < 8; ++j)
    y[j] = (x[j] - mean) * rstd * g[t * 8 + j] + b[t * 8 + j];
  if constexpr (F32OUT) {
    float* out = (float*)outp;
    f32x4 lo = {y[0], y[1], y[2], y[3]};
    f32x4 hi = {y[4], y[5], y[6], y[7]};
    *(f32x4*)&out[base + t * 8]     = lo;
    *(f32x4*)&out[base + t * 8 + 4] = hi;
  } else {
    u16* out = (u16*)outp;
    u16 o8[8];
    #pragma unroll
    for (int j = 0; j < 8; ++j) o8[j] = f2bf(y[j]);
    *(uint4*)&out[base + t * 8] = *(uint4*)o8;
  }
}

// ---------------------------------------------------------------------------
extern "C" void kernel_launch(void* const* d_in, const int* in_sizes, int n_in,
                              void* d_out, int out_size, void* d_ws, size_t ws_size,
                              hipStream_t stream) {
  // All reference dtypes are float32.
  const float* x      = (const float*)d_in[0];
  const float* amp_w  = (const float*)d_in[1];
  const float* amp_b  = (const float*)d_in[2];
  const float* ph_w   = (const float*)d_in[3];
  const float* ph_b   = (const float*)d_in[4];
  const float* ent_w  = (const float*)d_in[5];
  const float* ent_b  = (const float*)d_in[6];
  const float* ent_pw = (const float*)d_in[7];
  const float* ent_pb = (const float*)d_in[8];
  const float* path_w = (const float*)d_in[9];
  const float* path_b = (const float*)d_in[10];
  const float* phase  = (const float*)d_in[11];
  const float* ln3_g  = (const float*)d_in[12];
  const float* ln3_b  = (const float*)d_in[13];
  const float* ln4_g  = (const float*)d_in[14];
  const float* ln4_b  = (const float*)d_in[15];

  constexpr int D = 2048, PD = 8192, M = 4096, L = 2, PW = 2;
  constexpr int HPD = PD / 2;   // 4096 = slab width for entanglement layer

  // Workspace arena: 64 KiB floats + 112 MiB bf16 = well under 128 MiB.
  // Small buffers FIRST so any ws tightness hits large buffers we verified.
  char* p = (char*)d_ws;
  float* modf = (float*)p; p += (size_t)L * PW * D * sizeof(float);  // 32 KB
  float* bcf  = (float*)p; p += (size_t)2 * D * sizeof(float);       // 16 KB
  p = (char*)d_ws + 65536;                                           // pad to 64 KiB
  u16* h  = (u16*)p; p += (size_t)M * D * sizeof(u16);    // 16 MiB
  u16* t1 = (u16*)p; p += (size_t)M * D * sizeof(u16);    // 16 MiB
  u16* wT = (u16*)p; p += (size_t)HPD * D * sizeof(u16);  // 16 MiB (slab weight)
  u16* e  = (u16*)p; p += (size_t)M * PD * sizeof(u16);   // 64 MiB

  u16* xb = e;                      // bf16 copy of x (dead once zc computed)
  u16* zc = e + (size_t)M * D;      // [M][2D] fused amp/ph pre-activations

  dim3 b256(256);

  mod_k<<<(L * PW * D) / 256, b256, 0, stream>>>(phase, modf, L * PW * D);
  cvt_f2bf<<<(M * D) / (256 * 8), b256, 0, stream>>>(x, xb);

  // superposition: zc = x @ [amp_w | ph_w] + [amp_b | ph_b] ; h = f(zc)
  transpose_f2bf<<<dim3(D / 64, D / 64), b256, 0, stream>>>(amp_w, wT, D, D, D, 0);
  transpose_f2bf<<<dim3(D / 64, D / 64), b256, 0, stream>>>(ph_w, wT + (size_t)D * D, D, D, D, 0);
  concat2_k<<<D / 256, b256, 0, stream>>>(amp_b, ph_b, bcf, D);
  gemm_bt<false><<<dim3(M / BM, (2 * D) / BN), b256, 0, stream>>>(
      xb, D, wT, bcf, zc, 2 * D, M, 2 * D, D);
  superpose_k<<<(M * D) / (256 * 8), b256, 0, stream>>>(zc, h, D);

  for (int l = 0; l < L; ++l) {
    // e = h @ ent_w[l] + ent_b[l]   [M, PD], in two N-slabs of HPD
    for (int s = 0; s < 2; ++s) {
      // wT[n][k] = ent_w[l][k][s*HPD + n],  n<HPD, k<D
      transpose_f2bf<<<dim3(HPD / 64, D / 64), b256, 0, stream>>>(
          ent_w + (size_t)l * D * PD, wT, D, HPD, PD, s * HPD);
      gemm_bt<false><<<dim3(M / BM, HPD / BN), b256, 0, stream>>>(
          h, D, wT, ent_b + (size_t)l * PD + s * HPD, e + s * HPD, PD, M, HPD, D);
    }
    // ent = e @ ent_pw[l] + ent_pb[l]   [M, D], in two K-slabs of HPD
    for (int s = 0; s < 2; ++s) {
      // wT[n][k] = ent_pw[l][s*HPD + k][n],  n<D, k<HPD
      transpose_f2bf<<<dim3(D / 64, HPD / 64), b256, 0, stream>>>(
          ent_pw + (size_t)l * PD * D + (size_t)s * HPD * D, wT, HPD, D, D, 0);
      if (s == 0)
        gemm_bt<false><<<dim3(M / BM, D / BN), b256, 0, stream>>>(
            e, PD, wT, ent_pb + (size_t)l * D, t1, D, M, D, HPD);
      else
        gemm_bt<true><<<dim3(M / BM, D / BN), b256, 0, stream>>>(
            e + HPD, PD, wT, bcf /*ignored*/, t1, D, M, D, HPD);
    }
    // h = LN(h + ent)
    add_ln_k<false><<<M, b256, 0, stream>>>(h, t1, ln3_g + (size_t)l * D, ln3_b + (size_t)l * D, h, D);
    // interf = h @ Wc + bc   (PW=2 pathways folded into one matrix)
    combine_path_k<<<dim3(D / 64, D / 64), b256, 0, stream>>>(
        path_w + (size_t)l * PW * D * D, modf + (size_t)l * PW * D, wT, D);
    combine_bias_k<<<D / 256, b256, 0, stream>>>(path_b + (size_t)l * PW * D, modf + (size_t)l * PW * D, bcf, D);
    gemm_bt<false><<<dim3(M / BM, D / BN), b256, 0, stream>>>(
        h, D, wT, bcf, t1, D, M, D, D);
    // h = LN(h + interf); final layer writes f32 d_out
    if (l == L - 1)
      add_ln_k<true><<<M, b256, 0, stream>>>(h, t1, ln4_g + (size_t)l * D, ln4_b + (size_t)l * D, d_out, D);
    else
      add_ln_k<false><<<M, b256, 0, stream>>>(h, t1, ln4_g + (size_t)l * D, ln4_b + (size_t)l * D, h, D);
  }
}